// Round 6
// baseline (668.107 us; speedup 1.0000x reference)
//
#include <hip/hip_runtime.h>
#include <hip/hip_bf16.h>

#define N_NODES 100000
#define N_EDGES 1600000
#define IN_C 128
#define HID_C 256
#define OUT_C 128

typedef __attribute__((ext_vector_type(8))) short bf16x8;
typedef __attribute__((ext_vector_type(4))) float f32x4;
typedef __attribute__((ext_vector_type(2))) float f32x2;

static __device__ __forceinline__ short f2bf(float f) {
    union { float f; unsigned u; } x{f};
    unsigned r = (x.u + 0x7fffu + ((x.u >> 16) & 1u)) >> 16;
    return (short)r;
}
// unpack 2 bf16 (packed in one dword) -> f32 pair
static __device__ __forceinline__ f32x2 bfpair(unsigned d) {
    union { unsigned u; float f; } lo, hi;
    lo.u = d << 16;
    hi.u = d & 0xffff0000u;
    return f32x2{lo.f, hi.f};
}

// ================= fused cast (x,W1,W2,W3 -> bf16) + degree histogram =================
// cast chunk count is a multiple of 64 -> no intra-wave divergence at the seam.
__global__ void cast_hist(const float* __restrict__ s0, short* __restrict__ d0, int n0,
                          const float* __restrict__ s1, short* __restrict__ d1, int n1,
                          const float* __restrict__ s2, short* __restrict__ d2, int n2,
                          const float* __restrict__ s3, short* __restrict__ d3, int n3,
                          const int* __restrict__ rows, int* __restrict__ deg, int E)
{
    int idx = blockIdx.x * blockDim.x + threadIdx.x;
    int castN = (n0 + n1 + n2 + n3) / 4;
    if (idx < castN) {
        int i = idx * 4;
        const float* s; short* d;
        if (i < n0) { s = s0; d = d0; }
        else if ((i -= n0) < n1) { s = s1; d = d1; }
        else if ((i -= n1) < n2) { s = s2; d = d2; }
        else { i -= n2; s = s3; d = d3; }
        float4 v = *(const float4*)(s + i);
        *(short4*)(d + i) = short4{f2bf(v.x), f2bf(v.y), f2bf(v.z), f2bf(v.w)};
    } else {
        int e = idx - castN;
        if (e < E) atomicAdd(&deg[rows[e]], 1);
    }
}

// ================= CSR build =================
#define SCAN_BLOCK 256
#define SCAN_ELEMS 1024

__global__ __launch_bounds__(SCAN_BLOCK) void scan1(const int* __restrict__ deg,
                                                    int* __restrict__ excl,
                                                    int* __restrict__ bsum, int N)
{
    __shared__ int sh[SCAN_BLOCK];
    int t = threadIdx.x;
    int base = blockIdx.x * SCAN_ELEMS + t * 4;
    int v[4];
    #pragma unroll
    for (int i = 0; i < 4; ++i) {
        int idx = base + i;
        v[i] = (idx < N) ? deg[idx] : 0;
    }
    int s = v[0] + v[1] + v[2] + v[3];
    sh[t] = s;
    __syncthreads();
    for (int d = 1; d < SCAN_BLOCK; d <<= 1) {
        int add = (t >= d) ? sh[t - d] : 0;
        __syncthreads();
        sh[t] += add;
        __syncthreads();
    }
    int p = sh[t] - s;
    #pragma unroll
    for (int i = 0; i < 4; ++i) {
        int idx = base + i;
        if (idx < N) excl[idx] = p;
        p += v[i];
    }
    if (t == SCAN_BLOCK - 1) bsum[blockIdx.x] = sh[t];
}

__global__ void scan2(const int* __restrict__ bsum, int* __restrict__ boff, int NB)
{
    __shared__ int sh[128];
    int t = threadIdx.x;
    int v = (t < NB) ? bsum[t] : 0;
    sh[t] = v;
    __syncthreads();
    for (int d = 1; d < 128; d <<= 1) {
        int add = (t >= d) ? sh[t - d] : 0;
        __syncthreads();
        sh[t] += add;
        __syncthreads();
    }
    if (t < NB) boff[t] = sh[t] - v;
}

__global__ void scan3(int* __restrict__ row_start, const int* __restrict__ boff,
                      int* __restrict__ cursor, int N, int E)
{
    int i = blockIdx.x * blockDim.x + threadIdx.x;
    if (i < N) {
        int v = row_start[i] + boff[i >> 10];
        row_start[i] = v;
        cursor[i] = v;
    } else if (i == N) {
        row_start[N] = E;
    }
}

__global__ void scatter_edges(const int* __restrict__ rows, const int* __restrict__ cols,
                              const float* __restrict__ vals, int* __restrict__ cursor,
                              int2* __restrict__ epk, int E)
{
    int e = blockIdx.x * blockDim.x + threadIdx.x;
    if (e < E) {
        int r = rows[e];
        int pos = atomicAdd(&cursor[r], 1);
        epk[pos] = int2{cols[e], __float_as_int(vals[e])};
    }
}

// ================= gather SpMM, batched (8 edges in flight) =================
template<int B, int ND>
static __device__ __forceinline__ void spmm_batch(
    const unsigned* __restrict__ Hb, const int2* __restrict__ epk,
    int j, int loff, f32x2* acc)
{
    int2 e[B];
    #pragma unroll
    for (int b = 0; b < B; ++b) e[b] = epk[j + b];
    uint2 g[B];
    #pragma unroll
    for (int b = 0; b < B; ++b) {
        const unsigned* p = Hb + (size_t)e[b].x * (64 * ND) + loff;
        if constexpr (ND == 2) g[b] = *(const uint2*)p;
        else                   g[b].x = *p;
    }
    #pragma unroll
    for (int b = 0; b < B; ++b) {
        float v = __int_as_float(e[b].y);
        acc[0] += v * bfpair(g[b].x);
        if constexpr (ND == 2) acc[1] += v * bfpair(g[b].y);
    }
}

// MODE 0: write bf16. MODE 2: (C==128) add bias, L2-normalize row, write fp32.
template<int C, int MODE>
__global__ __launch_bounds__(256) void spmm_gather(
    const short* __restrict__ H, const int* __restrict__ row_start,
    const int2* __restrict__ epk, void* __restrict__ outv,
    const float* __restrict__ bias, int N)
{
    constexpr int PL = C / 64;
    constexpr int ND = PL / 2;
    int wid = threadIdx.x >> 6;
    int lane = threadIdx.x & 63;
    int row = blockIdx.x * 4 + wid;
    if (row >= N) return;
    int j = row_start[row];
    int end = row_start[row + 1];
    const unsigned* Hb = (const unsigned*)H;
    const int loff = lane * ND;

    f32x2 acc[ND];
    #pragma unroll
    for (int d = 0; d < ND; ++d) acc[d] = f32x2{0.f, 0.f};

    for (; j + 8 <= end; j += 8) spmm_batch<8, ND>(Hb, epk, j, loff, acc);
    if (j + 4 <= end) { spmm_batch<4, ND>(Hb, epk, j, loff, acc); j += 4; }
    if (j + 2 <= end) { spmm_batch<2, ND>(Hb, epk, j, loff, acc); j += 2; }
    if (j < end)      { spmm_batch<1, ND>(Hb, epk, j, loff, acc); }

    if constexpr (MODE == 0) {
        unsigned od[ND];
        #pragma unroll
        for (int d = 0; d < ND; ++d)
            od[d] = (unsigned)(unsigned short)f2bf(acc[d].x)
                  | ((unsigned)(unsigned short)f2bf(acc[d].y) << 16);
        unsigned* orow = (unsigned*)outv + (size_t)row * (64 * ND) + loff;
        if constexpr (ND == 2) *(uint2*)orow = uint2{od[0], od[1]};
        else                   *orow = od[0];
    } else {
        int ch = lane * 2;
        float o0 = acc[0].x + bias[ch];
        float o1 = acc[0].y + bias[ch + 1];
        float ss = o0 * o0 + o1 * o1;
        #pragma unroll
        for (int d = 1; d < 64; d <<= 1)
            ss += __shfl_xor(ss, d);
        float s = 1.0f / fmaxf(sqrtf(ss), 1e-12f);
        *(float2*)((float*)outv + (size_t)row * C + ch) = float2{o0 * s, o1 * s};
    }
}

// ================= bf16 MFMA GEMM, 128x128 block tile =================
// A: [N,K] bf16; W: [M,K] bf16; Y: [N,M] bf16. 4 waves (2x2), each 64x64 via 4x4 MFMA.
template<int K, int M, bool RELU, bool BIAS>
__global__ __launch_bounds__(256) void gemm_bf16(
    const short* __restrict__ A, const short* __restrict__ W,
    const float* __restrict__ bias, short* __restrict__ Y, int N)
{
    constexpr int BK = 32;
    constexpr int PAD = 8;   // 16B pad: ds_read_b128 stays 16B-aligned, 2-way max conflict
    __shared__ short As[128][BK + PAD];
    __shared__ short Ws[128][BK + PAD];

    const int tid = threadIdx.x;
    const int wid = tid >> 6;
    const int lane = tid & 63;
    const int wm = wid & 1;    // n-half
    const int wn = wid >> 1;   // m-half
    const int l15 = lane & 15;
    const int quad = lane >> 4;
    const int bn = blockIdx.x * 128;
    const int bm = blockIdx.y * 128;

    f32x4 acc[4][4] = {};

    for (int k0 = 0; k0 < K; k0 += BK) {
        // stage A tile: 128 rows x 32 k = 512 x 16B chunks, 2/thread
        #pragma unroll
        for (int c = 0; c < 2; ++c) {
            int chunk = tid + c * 256;
            int row = chunk >> 2;
            int koff = (chunk & 3) * 8;
            int gr = bn + row;
            ulonglong2 v = {0ull, 0ull};
            if (gr < N) v = *(const ulonglong2*)(A + (size_t)gr * K + k0 + koff);
            *(ulonglong2*)&As[row][koff] = v;
        }
        // stage W tile: 128 rows x 32 k, 2/thread (M multiple of 128, no guard)
        #pragma unroll
        for (int c = 0; c < 2; ++c) {
            int chunk = tid + c * 256;
            int row = chunk >> 2;
            int koff = (chunk & 3) * 8;
            ulonglong2 v = *(const ulonglong2*)(W + (size_t)(bm + row) * K + k0 + koff);
            *(ulonglong2*)&Ws[row][koff] = v;
        }
        __syncthreads();

        bf16x8 aF[4], bF[4];
        #pragma unroll
        for (int mt = 0; mt < 4; ++mt)
            aF[mt] = *(const bf16x8*)&As[wm * 64 + mt * 16 + l15][quad * 8];
        #pragma unroll
        for (int nt = 0; nt < 4; ++nt)
            bF[nt] = *(const bf16x8*)&Ws[wn * 64 + nt * 16 + l15][quad * 8];

        #pragma unroll
        for (int mt = 0; mt < 4; ++mt)
            #pragma unroll
            for (int nt = 0; nt < 4; ++nt)
                acc[mt][nt] = __builtin_amdgcn_mfma_f32_16x16x32_bf16(
                    aF[mt], bF[nt], acc[mt][nt], 0, 0, 0);
        __syncthreads();
    }

    // epilogue: C/D layout col=lane&15 (m), row=quad*4+r (n)
    #pragma unroll
    for (int nt = 0; nt < 4; ++nt) {
        int col = bm + wn * 64 + nt * 16 + l15;
        float bv = BIAS ? bias[col] : 0.f;
        #pragma unroll
        for (int mt = 0; mt < 4; ++mt) {
            int row0 = bn + wm * 64 + mt * 16 + quad * 4;
            #pragma unroll
            for (int r = 0; r < 4; ++r) {
                int row = row0 + r;
                if (row < N) {
                    float v = acc[mt][nt][r] + bv;
                    if (RELU) v = fmaxf(v, 0.f);
                    Y[(size_t)row * M + col] = f2bf(v);
                }
            }
        }
    }
}

extern "C" void kernel_launch(void* const* d_in, const int* in_sizes, int n_in,
                              void* d_out, int out_size, void* d_ws, size_t ws_size,
                              hipStream_t stream) {
    const float* x        = (const float*)d_in[0];
    const int*   edge_row = (const int*)d_in[1];
    const int*   edge_col = (const int*)d_in[2];
    const float* edge_val = (const float*)d_in[3];
    const float* W1       = (const float*)d_in[4];
    const float* b1       = (const float*)d_in[5];
    const float* W2       = (const float*)d_in[6];
    const float* b2       = (const float*)d_in[7];
    const float* W3       = (const float*)d_in[8];
    const float* b3       = (const float*)d_in[9];
    float* out = (float*)d_out;

    const int N = N_NODES, E = N_EDGES;
    const int NB = (N + SCAN_ELEMS - 1) / SCAN_ELEMS;   // 98

    // workspace layout
    short* xbf = (short*)d_ws;                    // [N,128] bf16
    short* Hbf = xbf + (size_t)N * IN_C;          // [N,256] bf16
    short* Gbf = Hbf + (size_t)N * HID_C;         // [N,256] bf16
    short* W1b = Gbf + (size_t)N * HID_C;         // [256,128]
    short* W2b = W1b + HID_C * IN_C;              // [256,256]
    short* W3b = W2b + HID_C * HID_C;             // [128,256]
    int* deg = (int*)(((uintptr_t)(W3b + OUT_C * HID_C) + 15) & ~(uintptr_t)15);
    int* row_start = deg + N;                     // [N+1]
    int* cursor    = row_start + (N + 1);
    int* bsum      = cursor + N;
    int* boff      = bsum + 128;
    int2* epk      = (int2*)(((uintptr_t)(boff + 128) + 15) & ~(uintptr_t)15);  // [E]

    // ---- fused casts + degree histogram ----
    hipMemsetAsync(deg, 0, N * sizeof(int), stream);
    {
        int n0 = N * IN_C, n1 = HID_C * IN_C, n2 = HID_C * HID_C, n3 = OUT_C * HID_C;
        int castN = (n0 + n1 + n2 + n3) / 4;      // multiple of 64
        int total = castN + E;
        cast_hist<<<(total + 255) / 256, 256, 0, stream>>>(
            x, xbf, n0, W1, W1b, n1, W2, W2b, n2, W3, W3b, n3, edge_row, deg, E);
    }
    // ---- rest of CSR build ----
    scan1<<<NB, SCAN_BLOCK, 0, stream>>>(deg, row_start, bsum, N);
    scan2<<<1, 128, 0, stream>>>(bsum, boff, NB);
    scan3<<<(N + 256) / 256, 256, 0, stream>>>(row_start, boff, cursor, N, E);
    scatter_edges<<<(E + 255) / 256, 256, 0, stream>>>(edge_row, edge_col, edge_val,
                                                       cursor, epk, E);

    const int spmm_grid = (N + 3) / 4;
    const int gemm_gx = (N + 127) / 128;

    // Layer 1: Hbf = spmm(xbf) [N,128]; Gbf = relu(Hbf@W1.T+b1) [N,256]
    spmm_gather<IN_C, 0><<<spmm_grid, 256, 0, stream>>>(
        xbf, row_start, epk, Hbf, nullptr, N);
    gemm_bf16<IN_C, HID_C, true, true><<<dim3(gemm_gx, HID_C / 128), 256, 0, stream>>>(
        Hbf, W1b, b1, Gbf, N);

    // Layer 2: Hbf = spmm(Gbf) [N,256]; Gbf = relu(Hbf@W2.T+b2) [N,256]
    spmm_gather<HID_C, 0><<<spmm_grid, 256, 0, stream>>>(
        Gbf, row_start, epk, Hbf, nullptr, N);
    gemm_bf16<HID_C, HID_C, true, true><<<dim3(gemm_gx, HID_C / 128), 256, 0, stream>>>(
        Hbf, W2b, b2, Gbf, N);

    // Layer 3: Hbf = Gbf@W3.T [N,128]; out = normalize(spmm(Hbf) + b3)  (fused)
    gemm_bf16<HID_C, OUT_C, false, false><<<dim3(gemm_gx, OUT_C / 128), 256, 0, stream>>>(
        Gbf, W3b, nullptr, Hbf, N);
    spmm_gather<OUT_C, 2><<<spmm_grid, 256, 0, stream>>>(
        Hbf, row_start, epk, out, b3, N);
}

// Round 7
// 598.118 us; speedup vs baseline: 1.1170x; 1.1170x over previous
//
#include <hip/hip_runtime.h>
#include <hip/hip_bf16.h>

#define N_NODES 100000
#define N_EDGES 1600000
#define IN_C 128
#define HID_C 256
#define OUT_C 128

typedef __attribute__((ext_vector_type(8))) short bf16x8;
typedef __attribute__((ext_vector_type(4))) float f32x4;
typedef __attribute__((ext_vector_type(2))) float f32x2;

static __device__ __forceinline__ short f2bf(float f) {
    union { float f; unsigned u; } x{f};
    unsigned r = (x.u + 0x7fffu + ((x.u >> 16) & 1u)) >> 16;
    return (short)r;
}
static __device__ __forceinline__ f32x2 bfpair(unsigned d) {
    union { unsigned u; float f; } lo, hi;
    lo.u = d << 16;
    hi.u = d & 0xffff0000u;
    return f32x2{lo.f, hi.f};
}

// ================= CSR build =================
// histogram + per-edge rank (stable within row): rank store is coalesced.
__global__ void hist_rank(const int* __restrict__ rows, int* __restrict__ deg,
                          int* __restrict__ rank, int E)
{
    int e = blockIdx.x * blockDim.x + threadIdx.x;
    if (e < E) rank[e] = atomicAdd(&deg[rows[e]], 1);
}

#define SCAN_BLOCK 256
#define SCAN_ELEMS 1024

__global__ __launch_bounds__(SCAN_BLOCK) void scan1(const int* __restrict__ deg,
                                                    int* __restrict__ excl,
                                                    int* __restrict__ bsum, int N)
{
    __shared__ int sh[SCAN_BLOCK];
    int t = threadIdx.x;
    int base = blockIdx.x * SCAN_ELEMS + t * 4;
    int v[4];
    #pragma unroll
    for (int i = 0; i < 4; ++i) {
        int idx = base + i;
        v[i] = (idx < N) ? deg[idx] : 0;
    }
    int s = v[0] + v[1] + v[2] + v[3];
    sh[t] = s;
    __syncthreads();
    for (int d = 1; d < SCAN_BLOCK; d <<= 1) {
        int add = (t >= d) ? sh[t - d] : 0;
        __syncthreads();
        sh[t] += add;
        __syncthreads();
    }
    int p = sh[t] - s;
    #pragma unroll
    for (int i = 0; i < 4; ++i) {
        int idx = base + i;
        if (idx < N) excl[idx] = p;
        p += v[i];
    }
    if (t == SCAN_BLOCK - 1) bsum[blockIdx.x] = sh[t];
}

__global__ void scan2(const int* __restrict__ bsum, int* __restrict__ boff, int NB)
{
    __shared__ int sh[128];
    int t = threadIdx.x;
    int v = (t < NB) ? bsum[t] : 0;
    sh[t] = v;
    __syncthreads();
    for (int d = 1; d < 128; d <<= 1) {
        int add = (t >= d) ? sh[t - d] : 0;
        __syncthreads();
        sh[t] += add;
        __syncthreads();
    }
    if (t < NB) boff[t] = sh[t] - v;
}

__global__ void scan3(int* __restrict__ row_start, const int* __restrict__ boff, int N, int E)
{
    int i = blockIdx.x * blockDim.x + threadIdx.x;
    if (i < N) {
        row_start[i] = row_start[i] + boff[i >> 10];
    } else if (i == N) {
        row_start[N] = E;
    }
}

// atomic-free scatter: pos is deterministic from row_start + rank
__global__ void scatter_edges(const int* __restrict__ rows, const int* __restrict__ cols,
                              const float* __restrict__ vals, const int* __restrict__ row_start,
                              const int* __restrict__ rank, int2* __restrict__ epk, int E)
{
    int e = blockIdx.x * blockDim.x + threadIdx.x;
    if (e < E) {
        int pos = row_start[rows[e]] + rank[e];
        epk[pos] = int2{cols[e], __float_as_int(vals[e])};
    }
}

// ================= fused casts (x, W1, W2, W3 -> bf16) =================
__global__ void cast_all(const float* __restrict__ s0, short* __restrict__ d0, int n0,
                         const float* __restrict__ s1, short* __restrict__ d1, int n1,
                         const float* __restrict__ s2, short* __restrict__ d2, int n2,
                         const float* __restrict__ s3, short* __restrict__ d3, int n3)
{
    int i = (blockIdx.x * blockDim.x + threadIdx.x) * 4;
    const float* s; short* d;
    if (i < n0) { s = s0; d = d0; }
    else if ((i -= n0) < n1) { s = s1; d = d1; }
    else if ((i -= n1) < n2) { s = s2; d = d2; }
    else if ((i -= n2) < n3) { s = s3; d = d3; }
    else return;
    float4 v = *(const float4*)(s + i);
    *(short4*)(d + i) = short4{f2bf(v.x), f2bf(v.y), f2bf(v.z), f2bf(v.w)};
}

// ================= gather SpMM, batched (8 edges in flight) =================
template<int B, int ND>
static __device__ __forceinline__ void spmm_batch(
    const unsigned* __restrict__ Hb, const int2* __restrict__ epk,
    int j, int loff, f32x2* acc)
{
    int2 e[B];
    #pragma unroll
    for (int b = 0; b < B; ++b) e[b] = epk[j + b];
    uint2 g[B];
    #pragma unroll
    for (int b = 0; b < B; ++b) {
        const unsigned* p = Hb + (size_t)e[b].x * (64 * ND) + loff;
        if constexpr (ND == 2) g[b] = *(const uint2*)p;
        else                   g[b].x = *p;
    }
    #pragma unroll
    for (int b = 0; b < B; ++b) {
        float v = __int_as_float(e[b].y);
        acc[0] += v * bfpair(g[b].x);
        if constexpr (ND == 2) acc[1] += v * bfpair(g[b].y);
    }
}

// MODE 0: write bf16. MODE 2: (C==128) add bias, L2-normalize row, write fp32.
template<int C, int MODE>
__global__ __launch_bounds__(256) void spmm_gather(
    const short* __restrict__ H, const int* __restrict__ row_start,
    const int2* __restrict__ epk, void* __restrict__ outv,
    const float* __restrict__ bias, int N)
{
    constexpr int PL = C / 64;
    constexpr int ND = PL / 2;
    int wid = threadIdx.x >> 6;
    int lane = threadIdx.x & 63;
    int row = blockIdx.x * 4 + wid;
    if (row >= N) return;
    int j = row_start[row];
    int end = row_start[row + 1];
    const unsigned* Hb = (const unsigned*)H;
    const int loff = lane * ND;

    f32x2 acc[ND];
    #pragma unroll
    for (int d = 0; d < ND; ++d) acc[d] = f32x2{0.f, 0.f};

    for (; j + 8 <= end; j += 8) spmm_batch<8, ND>(Hb, epk, j, loff, acc);
    if (j + 4 <= end) { spmm_batch<4, ND>(Hb, epk, j, loff, acc); j += 4; }
    if (j + 2 <= end) { spmm_batch<2, ND>(Hb, epk, j, loff, acc); j += 2; }
    if (j < end)      { spmm_batch<1, ND>(Hb, epk, j, loff, acc); }

    if constexpr (MODE == 0) {
        unsigned od[ND];
        #pragma unroll
        for (int d = 0; d < ND; ++d)
            od[d] = (unsigned)(unsigned short)f2bf(acc[d].x)
                  | ((unsigned)(unsigned short)f2bf(acc[d].y) << 16);
        unsigned* orow = (unsigned*)outv + (size_t)row * (64 * ND) + loff;
        if constexpr (ND == 2) *(uint2*)orow = uint2{od[0], od[1]};
        else                   *orow = od[0];
    } else {
        int ch = lane * 2;
        float o0 = acc[0].x + bias[ch];
        float o1 = acc[0].y + bias[ch + 1];
        float ss = o0 * o0 + o1 * o1;
        #pragma unroll
        for (int d = 1; d < 64; d <<= 1)
            ss += __shfl_xor(ss, d);
        float s = 1.0f / fmaxf(sqrtf(ss), 1e-12f);
        *(float2*)((float*)outv + (size_t)row * C + ch) = float2{o0 * s, o1 * s};
    }
}

// ================= bf16 MFMA GEMM, 128x64 block tile (R5-proven) =================
template<int K, int M, bool RELU, bool BIAS>
__global__ __launch_bounds__(256) void gemm_bf16(
    const short* __restrict__ A, const short* __restrict__ W,
    const float* __restrict__ bias, short* __restrict__ Y, int N)
{
    constexpr int BK = 32;
    constexpr int PAD = 8;
    __shared__ short As[128][BK + PAD];
    __shared__ short Ws[64][BK + PAD];

    const int tid = threadIdx.x;
    const int wid = tid >> 6;
    const int lane = tid & 63;
    const int wm = wid & 1;
    const int wn = wid >> 1;
    const int l15 = lane & 15;
    const int quad = lane >> 4;
    const int bn = blockIdx.x * 128;
    const int bm = blockIdx.y * 64;

    f32x4 acc[4][2] = {};

    for (int k0 = 0; k0 < K; k0 += BK) {
        #pragma unroll
        for (int c = 0; c < 2; ++c) {
            int chunk = tid + c * 256;
            int row = chunk >> 2;
            int koff = (chunk & 3) * 8;
            int gr = bn + row;
            ulonglong2 v = {0ull, 0ull};
            if (gr < N) v = *(const ulonglong2*)(A + (size_t)gr * K + k0 + koff);
            *(ulonglong2*)&As[row][koff] = v;
        }
        {
            int row = tid >> 2;
            int koff = (tid & 3) * 8;
            ulonglong2 v = *(const ulonglong2*)(W + (size_t)(bm + row) * K + k0 + koff);
            *(ulonglong2*)&Ws[row][koff] = v;
        }
        __syncthreads();

        bf16x8 aF[4], bF[2];
        #pragma unroll
        for (int mt = 0; mt < 4; ++mt)
            aF[mt] = *(const bf16x8*)&As[wm * 64 + mt * 16 + l15][quad * 8];
        #pragma unroll
        for (int nt = 0; nt < 2; ++nt)
            bF[nt] = *(const bf16x8*)&Ws[wn * 32 + nt * 16 + l15][quad * 8];

        #pragma unroll
        for (int mt = 0; mt < 4; ++mt)
            #pragma unroll
            for (int nt = 0; nt < 2; ++nt)
                acc[mt][nt] = __builtin_amdgcn_mfma_f32_16x16x32_bf16(
                    aF[mt], bF[nt], acc[mt][nt], 0, 0, 0);
        __syncthreads();
    }

    #pragma unroll
    for (int nt = 0; nt < 2; ++nt) {
        int col = bm + wn * 32 + nt * 16 + l15;
        float bv = BIAS ? bias[col] : 0.f;
        #pragma unroll
        for (int mt = 0; mt < 4; ++mt) {
            int row0 = bn + wm * 64 + mt * 16 + quad * 4;
            #pragma unroll
            for (int r = 0; r < 4; ++r) {
                int row = row0 + r;
                if (row < N) {
                    float v = acc[mt][nt][r] + bv;
                    if (RELU) v = fmaxf(v, 0.f);
                    Y[(size_t)row * M + col] = f2bf(v);
                }
            }
        }
    }
}

extern "C" void kernel_launch(void* const* d_in, const int* in_sizes, int n_in,
                              void* d_out, int out_size, void* d_ws, size_t ws_size,
                              hipStream_t stream) {
    const float* x        = (const float*)d_in[0];
    const int*   edge_row = (const int*)d_in[1];
    const int*   edge_col = (const int*)d_in[2];
    const float* edge_val = (const float*)d_in[3];
    const float* W1       = (const float*)d_in[4];
    const float* b1       = (const float*)d_in[5];
    const float* W2       = (const float*)d_in[6];
    const float* b2       = (const float*)d_in[7];
    const float* W3       = (const float*)d_in[8];
    const float* b3       = (const float*)d_in[9];
    float* out = (float*)d_out;

    const int N = N_NODES, E = N_EDGES;
    const int NB = (N + SCAN_ELEMS - 1) / SCAN_ELEMS;   // 98

    // workspace layout
    short* xbf = (short*)d_ws;                    // [N,128] bf16
    short* Hbf = xbf + (size_t)N * IN_C;          // [N,256] bf16
    short* Gbf = Hbf + (size_t)N * HID_C;         // [N,256] bf16
    short* W1b = Gbf + (size_t)N * HID_C;         // [256,128]
    short* W2b = W1b + HID_C * IN_C;              // [256,256]
    short* W3b = W2b + HID_C * HID_C;             // [128,256]
    int* deg = (int*)(((uintptr_t)(W3b + OUT_C * HID_C) + 15) & ~(uintptr_t)15);
    int* row_start = deg + N;                     // [N+1]
    int* rank      = row_start + (N + 1);         // [E]
    int* bsum      = rank + E;
    int* boff      = bsum + 128;
    int2* epk      = (int2*)(((uintptr_t)(boff + 128) + 15) & ~(uintptr_t)15);  // [E]

    // ---- build CSR (atomic-free scatter via precomputed rank) ----
    hipMemsetAsync(deg, 0, N * sizeof(int), stream);
    hist_rank<<<(E + 255) / 256, 256, 0, stream>>>(edge_row, deg, rank, E);
    scan1<<<NB, SCAN_BLOCK, 0, stream>>>(deg, row_start, bsum, N);
    scan2<<<1, 128, 0, stream>>>(bsum, boff, NB);
    scan3<<<(N + 256) / 256, 256, 0, stream>>>(row_start, boff, N, E);
    scatter_edges<<<(E + 255) / 256, 256, 0, stream>>>(edge_row, edge_col, edge_val,
                                                       row_start, rank, epk, E);

    // ---- casts (fused) ----
    {
        int n0 = N * IN_C, n1 = HID_C * IN_C, n2 = HID_C * HID_C, n3 = OUT_C * HID_C;
        int total4 = (n0 + n1 + n2 + n3) / 4;
        cast_all<<<(total4 + 255) / 256, 256, 0, stream>>>(
            x, xbf, n0, W1, W1b, n1, W2, W2b, n2, W3, W3b, n3);
    }

    const int spmm_grid = (N + 3) / 4;
    const int gemm_gx = (N + 127) / 128;

    // Layer 1: Hbf = spmm(xbf) [N,128]; Gbf = relu(Hbf@W1.T+b1) [N,256]
    spmm_gather<IN_C, 0><<<spmm_grid, 256, 0, stream>>>(
        xbf, row_start, epk, Hbf, nullptr, N);
    gemm_bf16<IN_C, HID_C, true, true><<<dim3(gemm_gx, HID_C / 64), 256, 0, stream>>>(
        Hbf, W1b, b1, Gbf, N);

    // Layer 2: Hbf = spmm(Gbf) [N,256]; Gbf = relu(Hbf@W2.T+b2) [N,256]
    spmm_gather<HID_C, 0><<<spmm_grid, 256, 0, stream>>>(
        Gbf, row_start, epk, Hbf, nullptr, N);
    gemm_bf16<HID_C, HID_C, true, true><<<dim3(gemm_gx, HID_C / 64), 256, 0, stream>>>(
        Hbf, W2b, b2, Gbf, N);

    // Layer 3: Hbf = Gbf@W3.T [N,128]; out = normalize(spmm(Hbf) + b3)  (fused)
    gemm_bf16<HID_C, OUT_C, false, false><<<dim3(gemm_gx, OUT_C / 64), 256, 0, stream>>>(
        Gbf, W3b, nullptr, Hbf, N);
    spmm_gather<OUT_C, 2><<<spmm_grid, 256, 0, stream>>>(
        Hbf, row_start, epk, out, b3, N);
}

// Round 8
// 566.922 us; speedup vs baseline: 1.1785x; 1.0550x over previous
//
#include <hip/hip_runtime.h>
#include <hip/hip_bf16.h>

#define N_NODES 100000
#define N_EDGES 1600000
#define IN_C 128
#define HID_C 256
#define OUT_C 128

typedef __attribute__((ext_vector_type(8))) short bf16x8;
typedef __attribute__((ext_vector_type(4))) float f32x4;
typedef __attribute__((ext_vector_type(2))) float f32x2;

static __device__ __forceinline__ short f2bf(float f) {
    union { float f; unsigned u; } x{f};
    unsigned r = (x.u + 0x7fffu + ((x.u >> 16) & 1u)) >> 16;
    return (short)r;
}
static __device__ __forceinline__ f32x2 bfpair(unsigned d) {
    union { unsigned u; float f; } lo, hi;
    lo.u = d << 16;
    hi.u = d & 0xffff0000u;
    return f32x2{lo.f, hi.f};
}

// ================= CSR build =================
__global__ void hist_rank(const int* __restrict__ rows, int* __restrict__ deg,
                          int* __restrict__ rank, int E)
{
    int e = blockIdx.x * blockDim.x + threadIdx.x;
    if (e < E) rank[e] = atomicAdd(&deg[rows[e]], 1);
}

#define SCAN_BLOCK 256
#define SCAN_ELEMS 1024

__global__ __launch_bounds__(SCAN_BLOCK) void scan1(const int* __restrict__ deg,
                                                    int* __restrict__ excl,
                                                    int* __restrict__ bsum, int N)
{
    __shared__ int sh[SCAN_BLOCK];
    int t = threadIdx.x;
    int base = blockIdx.x * SCAN_ELEMS + t * 4;
    int v[4];
    #pragma unroll
    for (int i = 0; i < 4; ++i) {
        int idx = base + i;
        v[i] = (idx < N) ? deg[idx] : 0;
    }
    int s = v[0] + v[1] + v[2] + v[3];
    sh[t] = s;
    __syncthreads();
    for (int d = 1; d < SCAN_BLOCK; d <<= 1) {
        int add = (t >= d) ? sh[t - d] : 0;
        __syncthreads();
        sh[t] += add;
        __syncthreads();
    }
    int p = sh[t] - s;
    #pragma unroll
    for (int i = 0; i < 4; ++i) {
        int idx = base + i;
        if (idx < N) excl[idx] = p;
        p += v[i];
    }
    if (t == SCAN_BLOCK - 1) bsum[blockIdx.x] = sh[t];
}

// scan2 folded in: every block recomputes the (<=128-entry) block-sum prefix in LDS.
__global__ void scan3(int* __restrict__ row_start, const int* __restrict__ bsum,
                      int NB, int N, int E)
{
    __shared__ int pref[128];
    int t = threadIdx.x;
    if (t < 128) pref[t] = (t < NB) ? bsum[t] : 0;
    __syncthreads();
    for (int d = 1; d < 128; d <<= 1) {
        int add = (t < 128 && t >= d) ? pref[t - d] : 0;
        __syncthreads();
        if (t < 128) pref[t] += add;
        __syncthreads();
    }
    int i = blockIdx.x * blockDim.x + t;
    if (i < N) {
        int b = i >> 10;
        row_start[i] += (b == 0) ? 0 : pref[b - 1];
    } else if (i == N) {
        row_start[N] = E;
    }
}

// atomic-free scatter fused with bf16 casts (wave-aligned seam: E % 64 == 0)
__global__ void scatter_cast(const int* __restrict__ rows, const int* __restrict__ cols,
                             const float* __restrict__ vals, const int* __restrict__ row_start,
                             const int* __restrict__ rank, int2* __restrict__ epk, int E,
                             const float* __restrict__ s0, short* __restrict__ d0, int n0,
                             const float* __restrict__ s1, short* __restrict__ d1, int n1,
                             const float* __restrict__ s2, short* __restrict__ d2, int n2,
                             const float* __restrict__ s3, short* __restrict__ d3, int n3)
{
    int idx = blockIdx.x * blockDim.x + threadIdx.x;
    if (idx < E) {
        int pos = row_start[rows[idx]] + rank[idx];
        epk[pos] = int2{cols[idx], __float_as_int(vals[idx])};
    } else {
        int i = (idx - E) * 4;
        int castN = n0 + n1 + n2 + n3;
        if (i >= castN) return;
        const float* s; short* d;
        if (i < n0) { s = s0; d = d0; }
        else if ((i -= n0) < n1) { s = s1; d = d1; }
        else if ((i -= n1) < n2) { s = s2; d = d2; }
        else { i -= n2; s = s3; d = d3; }
        float4 v = *(const float4*)(s + i);
        *(short4*)(d + i) = short4{f2bf(v.x), f2bf(v.y), f2bf(v.z), f2bf(v.w)};
    }
}

// ================= gather SpMM, batched (8 edges in flight) =================
template<int B, int ND>
static __device__ __forceinline__ void spmm_batch(
    const unsigned* __restrict__ Hb, const int2* __restrict__ epk,
    int j, int loff, f32x2* acc)
{
    int2 e[B];
    #pragma unroll
    for (int b = 0; b < B; ++b) e[b] = epk[j + b];
    uint2 g[B];
    #pragma unroll
    for (int b = 0; b < B; ++b) {
        const unsigned* p = Hb + (size_t)e[b].x * (64 * ND) + loff;
        if constexpr (ND == 2) g[b] = *(const uint2*)p;
        else                   g[b].x = *p;
    }
    #pragma unroll
    for (int b = 0; b < B; ++b) {
        float v = __int_as_float(e[b].y);
        acc[0] += v * bfpair(g[b].x);
        if constexpr (ND == 2) acc[1] += v * bfpair(g[b].y);
    }
}

// MODE 0: write bf16. MODE 2: (C==128) add bias, L2-normalize row, write fp32.
template<int C, int MODE>
__global__ __launch_bounds__(256) void spmm_gather(
    const short* __restrict__ H, const int* __restrict__ row_start,
    const int2* __restrict__ epk, void* __restrict__ outv,
    const float* __restrict__ bias, int N)
{
    constexpr int PL = C / 64;
    constexpr int ND = PL / 2;
    int wid = threadIdx.x >> 6;
    int lane = threadIdx.x & 63;
    int row = blockIdx.x * 4 + wid;
    if (row >= N) return;
    int j = row_start[row];
    int end = row_start[row + 1];
    const unsigned* Hb = (const unsigned*)H;
    const int loff = lane * ND;

    f32x2 acc[ND];
    #pragma unroll
    for (int d = 0; d < ND; ++d) acc[d] = f32x2{0.f, 0.f};

    for (; j + 8 <= end; j += 8) spmm_batch<8, ND>(Hb, epk, j, loff, acc);
    if (j + 4 <= end) { spmm_batch<4, ND>(Hb, epk, j, loff, acc); j += 4; }
    if (j + 2 <= end) { spmm_batch<2, ND>(Hb, epk, j, loff, acc); j += 2; }
    if (j < end)      { spmm_batch<1, ND>(Hb, epk, j, loff, acc); }

    if constexpr (MODE == 0) {
        unsigned od[ND];
        #pragma unroll
        for (int d = 0; d < ND; ++d)
            od[d] = (unsigned)(unsigned short)f2bf(acc[d].x)
                  | ((unsigned)(unsigned short)f2bf(acc[d].y) << 16);
        unsigned* orow = (unsigned*)outv + (size_t)row * (64 * ND) + loff;
        if constexpr (ND == 2) *(uint2*)orow = uint2{od[0], od[1]};
        else                   *orow = od[0];
    } else {
        int ch = lane * 2;
        float o0 = acc[0].x + bias[ch];
        float o1 = acc[0].y + bias[ch + 1];
        float ss = o0 * o0 + o1 * o1;
        #pragma unroll
        for (int d = 1; d < 64; d <<= 1)
            ss += __shfl_xor(ss, d);
        float s = 1.0f / fmaxf(sqrtf(ss), 1e-12f);
        *(float2*)((float*)outv + (size_t)row * C + ch) = float2{o0 * s, o1 * s};
    }
}

// ================= bf16 MFMA GEMM, 128x64 tile, XCD-aware swizzle =================
// 1-D grid of GXP*MBLK blocks, GXP = padded strip count (multiple of 8).
// Swizzle: ids {g*8*MBLK + y*8 + x} -> strip bx = g*8+x, m-block by = y.
// With round-robin block->XCD dispatch, ids 8 apart share an XCD, so all MBLK
// users of one A-strip hit the same XCD L2 -> A fetched ~once instead of MBLK x.
template<int K, int M, bool RELU, bool BIAS>
__global__ __launch_bounds__(256) void gemm_bf16(
    const short* __restrict__ A, const short* __restrict__ W,
    const float* __restrict__ bias, short* __restrict__ Y, int N)
{
    constexpr int MBLK = M / 64;
    constexpr int BK = 32;
    constexpr int PAD = 8;
    __shared__ short As[128][BK + PAD];
    __shared__ short Ws[64][BK + PAD];

    const int id = blockIdx.x;
    const int bx = (id / (8 * MBLK)) * 8 + (id & 7);
    const int by = (id >> 3) & (MBLK - 1);

    const int tid = threadIdx.x;
    const int wid = tid >> 6;
    const int lane = tid & 63;
    const int wm = wid & 1;
    const int wn = wid >> 1;
    const int l15 = lane & 15;
    const int quad = lane >> 4;
    const int bn = bx * 128;
    const int bm = by * 64;

    f32x4 acc[4][2] = {};

    for (int k0 = 0; k0 < K; k0 += BK) {
        #pragma unroll
        for (int c = 0; c < 2; ++c) {
            int chunk = tid + c * 256;
            int row = chunk >> 2;
            int koff = (chunk & 3) * 8;
            int gr = bn + row;
            ulonglong2 v = {0ull, 0ull};
            if (gr < N) v = *(const ulonglong2*)(A + (size_t)gr * K + k0 + koff);
            *(ulonglong2*)&As[row][koff] = v;
        }
        {
            int row = tid >> 2;
            int koff = (tid & 3) * 8;
            ulonglong2 v = *(const ulonglong2*)(W + (size_t)(bm + row) * K + k0 + koff);
            *(ulonglong2*)&Ws[row][koff] = v;
        }
        __syncthreads();

        bf16x8 aF[4], bF[2];
        #pragma unroll
        for (int mt = 0; mt < 4; ++mt)
            aF[mt] = *(const bf16x8*)&As[wm * 64 + mt * 16 + l15][quad * 8];
        #pragma unroll
        for (int nt = 0; nt < 2; ++nt)
            bF[nt] = *(const bf16x8*)&Ws[wn * 32 + nt * 16 + l15][quad * 8];

        #pragma unroll
        for (int mt = 0; mt < 4; ++mt)
            #pragma unroll
            for (int nt = 0; nt < 2; ++nt)
                acc[mt][nt] = __builtin_amdgcn_mfma_f32_16x16x32_bf16(
                    aF[mt], bF[nt], acc[mt][nt], 0, 0, 0);
        __syncthreads();
    }

    #pragma unroll
    for (int nt = 0; nt < 2; ++nt) {
        int col = bm + wn * 32 + nt * 16 + l15;
        float bv = BIAS ? bias[col] : 0.f;
        #pragma unroll
        for (int mt = 0; mt < 4; ++mt) {
            int row0 = bn + wm * 64 + mt * 16 + quad * 4;
            #pragma unroll
            for (int r = 0; r < 4; ++r) {
                int row = row0 + r;
                if (row < N) {
                    float v = acc[mt][nt][r] + bv;
                    if (RELU) v = fmaxf(v, 0.f);
                    Y[(size_t)row * M + col] = f2bf(v);
                }
            }
        }
    }
}

extern "C" void kernel_launch(void* const* d_in, const int* in_sizes, int n_in,
                              void* d_out, int out_size, void* d_ws, size_t ws_size,
                              hipStream_t stream) {
    const float* x        = (const float*)d_in[0];
    const int*   edge_row = (const int*)d_in[1];
    const int*   edge_col = (const int*)d_in[2];
    const float* edge_val = (const float*)d_in[3];
    const float* W1       = (const float*)d_in[4];
    const float* b1       = (const float*)d_in[5];
    const float* W2       = (const float*)d_in[6];
    const float* b2       = (const float*)d_in[7];
    const float* W3       = (const float*)d_in[8];
    const float* b3       = (const float*)d_in[9];
    float* out = (float*)d_out;

    const int N = N_NODES, E = N_EDGES;
    const int NB = (N + SCAN_ELEMS - 1) / SCAN_ELEMS;   // 98

    // workspace layout
    short* xbf = (short*)d_ws;                    // [N,128] bf16
    short* Hbf = xbf + (size_t)N * IN_C;          // [N,256] bf16
    short* Gbf = Hbf + (size_t)N * HID_C;         // [N,256] bf16
    short* W1b = Gbf + (size_t)N * HID_C;         // [256,128]
    short* W2b = W1b + HID_C * IN_C;              // [256,256]
    short* W3b = W2b + HID_C * HID_C;             // [128,256]
    int* deg = (int*)(((uintptr_t)(W3b + OUT_C * HID_C) + 15) & ~(uintptr_t)15);
    int* row_start = deg + N;                     // [N+1]
    int* rank      = row_start + (N + 1);         // [E]
    int* bsum      = rank + E;                    // [128]
    int2* epk      = (int2*)(((uintptr_t)(bsum + 128) + 15) & ~(uintptr_t)15);  // [E]

    // ---- build CSR (atomic-free scatter) + casts ----
    hipMemsetAsync(deg, 0, N * sizeof(int), stream);
    hist_rank<<<(E + 255) / 256, 256, 0, stream>>>(edge_row, deg, rank, E);
    scan1<<<NB, SCAN_BLOCK, 0, stream>>>(deg, row_start, bsum, N);
    scan3<<<(N + 256) / 256, 256, 0, stream>>>(row_start, bsum, NB, N, E);
    {
        int n0 = N * IN_C, n1 = HID_C * IN_C, n2 = HID_C * HID_C, n3 = OUT_C * HID_C;
        int total = E + (n0 + n1 + n2 + n3) / 4;   // both parts wave-aligned
        scatter_cast<<<(total + 255) / 256, 256, 0, stream>>>(
            edge_row, edge_col, edge_val, row_start, rank, epk, E,
            x, xbf, n0, W1, W1b, n1, W2, W2b, n2, W3, W3b, n3);
    }

    const int spmm_grid = (N + 3) / 4;
    const int GXP = ((N + 127) / 128 + 7) & ~7;   // 784 padded strips (OOB strips guarded)

    // Layer 1: Hbf = spmm(xbf) [N,128]; Gbf = relu(Hbf@W1.T+b1) [N,256]
    spmm_gather<IN_C, 0><<<spmm_grid, 256, 0, stream>>>(
        xbf, row_start, epk, Hbf, nullptr, N);
    gemm_bf16<IN_C, HID_C, true, true><<<GXP * (HID_C / 64), 256, 0, stream>>>(
        Hbf, W1b, b1, Gbf, N);

    // Layer 2: Hbf = spmm(Gbf) [N,256]; Gbf = relu(Hbf@W2.T+b2) [N,256]
    spmm_gather<HID_C, 0><<<spmm_grid, 256, 0, stream>>>(
        Gbf, row_start, epk, Hbf, nullptr, N);
    gemm_bf16<HID_C, HID_C, true, true><<<GXP * (HID_C / 64), 256, 0, stream>>>(
        Hbf, W2b, b2, Gbf, N);

    // Layer 3: Hbf = Gbf@W3.T [N,128]; out = normalize(spmm(Hbf) + b3)  (fused)
    gemm_bf16<HID_C, OUT_C, false, false><<<GXP * (OUT_C / 64), 256, 0, stream>>>(
        Gbf, W3b, nullptr, Hbf, N);
    spmm_gather<OUT_C, 2><<<spmm_grid, 256, 0, stream>>>(
        Hbf, row_start, epk, out, b3, N);
}